// Round 1
// baseline (660.712 us; speedup 1.0000x reference)
//
#include <hip/hip_runtime.h>
#include <hip/hip_bf16.h>

#define Nn 16384
#define Ff 39
#define Vv 100000
#define Ee 16
#define Dd 624      // F*E
#define Hh 400
#define EPSf 1e-5f

// ---------------- Kernel 1: embedding gather + FM interactions ----------------
// one wave (64 lanes) per row; 4 rows per 256-thread block.
__global__ __launch_bounds__(256) void embed_kernel(
    const int* __restrict__ xi, const float* __restrict__ xv,
    const float* __restrict__ emb1, const float* __restrict__ emb2,
    const float* __restrict__ bias,
    float* __restrict__ deep, float* __restrict__ p) {
  __shared__ int   sidx[4][40];
  __shared__ float sxv[4][40];
  const int w = threadIdx.x >> 6;
  const int lane = threadIdx.x & 63;
  const int n = blockIdx.x * 4 + w;
  if (lane < Ff) {
    sidx[w][lane] = xi[n * Ff + lane];
    sxv[w][lane]  = xv[n * Ff + lane];
  }
  __syncthreads();

  float s_e = 0.f, sq_e = 0.f;
  #pragma unroll
  for (int j = lane; j < Dd; j += 64) {
    const int f = j >> 4, e = j & 15;
    const long off = ((long)f * (Vv + 1) + sidx[w][f]) * Ee + e;
    const float v = emb2[off] * sxv[w][f];
    deep[(long)n * Dd + j] = v;
    s_e += v; sq_e += v * v;
  }
  // combine the 4 lane-groups sharing the same e = lane&15
  s_e  += __shfl_xor(s_e, 16);  sq_e += __shfl_xor(sq_e, 16);
  s_e  += __shfl_xor(s_e, 32);  sq_e += __shfl_xor(sq_e, 32);

  float val = (lane < Ee) ? 0.5f * (s_e * s_e - sq_e) : 0.f;
  if (lane < Ff)
    val += emb1[(long)lane * (Vv + 1) + sidx[w][lane]] * sxv[w][lane];
  #pragma unroll
  for (int d = 1; d < 64; d <<= 1) val += __shfl_xor(val, d);
  if (lane == 0) p[n] = val + bias[0];
}

// ---------------- Kernel 2: fp32 GEMM  C = A(MxK) @ W(KxNc) + bias ----------------
// 64x64 block tile, BK=16, 256 threads, 4x4 microtile per thread.
__global__ __launch_bounds__(256) void gemm_kernel(
    const float* __restrict__ A, const float* __restrict__ W,
    const float* __restrict__ bias, float* __restrict__ C,
    int M, int K, int Nc) {
  __shared__ __align__(16) float As[16][64];
  __shared__ __align__(16) float Bs[16][68];
  const int tid = threadIdx.x;
  const int m0 = blockIdx.y * 64;
  const int n0 = blockIdx.x * 64;
  const int tx = tid & 15, ty = tid >> 4;
  const int arow = tid >> 2;           // 0..63
  const int akq  = (tid & 3) * 4;      // 0,4,8,12
  const int brow = tid >> 4;           // 0..15
  const int bnq  = (tid & 15) * 4;     // 0..60

  float acc[4][4] = {};
  for (int k0 = 0; k0 < K; k0 += 16) {
    float4 a = *(const float4*)&A[(long)(m0 + arow) * K + k0 + akq];
    As[akq + 0][arow] = a.x; As[akq + 1][arow] = a.y;
    As[akq + 2][arow] = a.z; As[akq + 3][arow] = a.w;
    if (n0 + bnq + 3 < Nc) {
      *(float4*)&Bs[brow][bnq] = *(const float4*)&W[(long)(k0 + brow) * Nc + n0 + bnq];
    } else {
      Bs[brow][bnq] = Bs[brow][bnq + 1] = Bs[brow][bnq + 2] = Bs[brow][bnq + 3] = 0.f;
    }
    __syncthreads();
    #pragma unroll
    for (int k = 0; k < 16; ++k) {
      float4 av = *(const float4*)&As[k][ty * 4];
      float4 bv = *(const float4*)&Bs[k][tx * 4];
      acc[0][0] += av.x * bv.x; acc[0][1] += av.x * bv.y; acc[0][2] += av.x * bv.z; acc[0][3] += av.x * bv.w;
      acc[1][0] += av.y * bv.x; acc[1][1] += av.y * bv.y; acc[1][2] += av.y * bv.z; acc[1][3] += av.y * bv.w;
      acc[2][0] += av.z * bv.x; acc[2][1] += av.z * bv.y; acc[2][2] += av.z * bv.z; acc[2][3] += av.z * bv.w;
      acc[3][0] += av.w * bv.x; acc[3][1] += av.w * bv.y; acc[3][2] += av.w * bv.z; acc[3][3] += av.w * bv.w;
    }
    __syncthreads();
  }
  const int nbase = n0 + tx * 4;
  if (nbase + 3 < Nc) {
    #pragma unroll
    for (int i = 0; i < 4; ++i) {
      const int m = m0 + ty * 4 + i;
      float4 o;
      o.x = acc[i][0] + bias[nbase + 0];
      o.y = acc[i][1] + bias[nbase + 1];
      o.z = acc[i][2] + bias[nbase + 2];
      o.w = acc[i][3] + bias[nbase + 3];
      *(float4*)&C[(long)m * Nc + nbase] = o;
    }
  }
}

// ---------------- Kernel 3: per-column sum & sumsq ----------------
__global__ __launch_bounds__(256) void stats_kernel(
    const float* __restrict__ X, float* __restrict__ s, float* __restrict__ ss, int M) {
  const int t = threadIdx.x;
  const int c0 = t, c1 = t + 256;
  float a0 = 0.f, q0 = 0.f, a1 = 0.f, q1 = 0.f;
  for (int r = blockIdx.x; r < M; r += gridDim.x) {
    const float x0 = X[(long)r * Hh + c0];
    a0 += x0; q0 += x0 * x0;
    if (c1 < Hh) {
      const float x1 = X[(long)r * Hh + c1];
      a1 += x1; q1 += x1 * x1;
    }
  }
  atomicAdd(&s[c0], a0); atomicAdd(&ss[c0], q0);
  if (c1 < Hh) { atomicAdd(&s[c1], a1); atomicAdd(&ss[c1], q1); }
}

// ---------------- Kernel 4: apply BN in place ----------------
__global__ __launch_bounds__(256) void bn_apply_kernel(
    float* __restrict__ X, const float* __restrict__ s, const float* __restrict__ ss,
    const float* __restrict__ g, const float* __restrict__ be, int M) {
  const float invM = 1.f / (float)M;
  long i = (long)blockIdx.x * blockDim.x + threadIdx.x;
  const long total = (long)M * Hh;
  const long stride = (long)gridDim.x * blockDim.x;
  for (; i < total; i += stride) {
    const int h = (int)(i % Hh);
    const float mu = s[h] * invM;
    const float var = ss[h] * invM - mu * mu;
    const float x = X[i];
    X[i] = g[h] * (x - mu) * rsqrtf(var + EPSf) + be[h];
  }
}

// ---------------- Kernel 5: alpha = g2*rsqrt(var2+eps); c2 = sum(be2 - alpha*mu2) ----------------
__global__ __launch_bounds__(512) void alpha_kernel(
    const float* __restrict__ s2, const float* __restrict__ ss2,
    const float* __restrict__ g2, const float* __restrict__ be2,
    float* __restrict__ alpha, float* __restrict__ c2, int M) {
  __shared__ float red[512];
  const int t = threadIdx.x;
  float part = 0.f;
  if (t < Hh) {
    const float mu = s2[t] / (float)M;
    const float var = ss2[t] / (float)M - mu * mu;
    const float al = g2[t] * rsqrtf(var + EPSf);
    alpha[t] = al;
    part = be2[t] - al * mu;
  }
  red[t] = part;
  __syncthreads();
  for (int d = 256; d > 0; d >>= 1) {
    if (t < d) red[t] += red[t + d];
    __syncthreads();
  }
  if (t == 0) c2[0] = red[0];
}

// ---------------- Kernel 6: out[n] = p[n] + dot(alpha, x2[n,:]) + c2 ----------------
__global__ __launch_bounds__(256) void final_kernel(
    const float* __restrict__ X2, const float* __restrict__ alpha,
    const float* __restrict__ p, const float* __restrict__ c2,
    float* __restrict__ out) {
  const int w = threadIdx.x >> 6, lane = threadIdx.x & 63;
  const int n = blockIdx.x * 4 + w;
  float acc = 0.f;
  for (int h = lane; h < Hh; h += 64)
    acc += X2[(long)n * Hh + h] * alpha[h];
  #pragma unroll
  for (int d = 1; d < 64; d <<= 1) acc += __shfl_xor(acc, d);
  if (lane == 0) out[n] = p[n] + acc + c2[0];
}

extern "C" void kernel_launch(void* const* d_in, const int* in_sizes, int n_in,
                              void* d_out, int out_size, void* d_ws, size_t ws_size,
                              hipStream_t stream) {
  const int*   xi   = (const int*)d_in[0];
  const float* xv   = (const float*)d_in[1];
  const float* emb1 = (const float*)d_in[2];
  const float* emb2 = (const float*)d_in[3];
  const float* W1   = (const float*)d_in[4];
  const float* b1   = (const float*)d_in[5];
  const float* g1   = (const float*)d_in[6];
  const float* be1  = (const float*)d_in[7];
  const float* W2   = (const float*)d_in[8];
  const float* b2   = (const float*)d_in[9];
  const float* g2   = (const float*)d_in[10];
  const float* be2  = (const float*)d_in[11];
  const float* bias = (const float*)d_in[12];
  float* out = (float*)d_out;

  float* ws   = (float*)d_ws;
  float* deep = ws;                               // N*624
  float* x1   = deep + (size_t)Nn * Dd;           // N*400
  float* x2   = x1 + (size_t)Nn * Hh;             // N*400
  float* p    = x2 + (size_t)Nn * Hh;             // N
  float* s1   = p + Nn;                           // 400
  float* ss1  = s1 + Hh;
  float* s2   = ss1 + Hh;
  float* ss2  = s2 + Hh;
  float* alpha = ss2 + Hh;
  float* c2   = alpha + Hh;                       // 1

  // zero the atomic stat accumulators (ws is re-poisoned before every call)
  hipMemsetAsync(s1, 0, 4 * Hh * sizeof(float), stream);

  embed_kernel<<<Nn / 4, 256, 0, stream>>>(xi, xv, emb1, emb2, bias, deep, p);

  gemm_kernel<<<dim3((Hh + 63) / 64, Nn / 64), 256, 0, stream>>>(deep, W1, b1, x1, Nn, Dd, Hh);
  stats_kernel<<<256, 256, 0, stream>>>(x1, s1, ss1, Nn);
  bn_apply_kernel<<<4096, 256, 0, stream>>>(x1, s1, ss1, g1, be1, Nn);

  gemm_kernel<<<dim3((Hh + 63) / 64, Nn / 64), 256, 0, stream>>>(x1, W2, b2, x2, Nn, Hh, Hh);
  stats_kernel<<<256, 256, 0, stream>>>(x2, s2, ss2, Nn);
  alpha_kernel<<<1, 512, 0, stream>>>(s2, ss2, g2, be2, alpha, c2, Nn);

  final_kernel<<<Nn / 4, 256, 0, stream>>>(x2, alpha, p, c2, out);
}

// Round 2
// 440.260 us; speedup vs baseline: 1.5007x; 1.5007x over previous
//
#include <hip/hip_runtime.h>
#include <hip/hip_bf16.h>

#define Nn 16384
#define Ff 39
#define Vv 100000
#define Ee 16
#define Dd 624      // F*E
#define Hh 400
#define EPSf 1e-5f

typedef short short8 __attribute__((ext_vector_type(8)));
typedef float floatx4 __attribute__((ext_vector_type(4)));

__device__ __forceinline__ float bf2f(unsigned short v) {
  union { unsigned int u; float f; } x; x.u = ((unsigned int)v) << 16; return x.f;
}

// ---------------- Kernel 1: embedding gather + FM interactions, bf16 deep ----------------
__global__ __launch_bounds__(256) void embed_kernel(
    const int* __restrict__ xi, const float* __restrict__ xv,
    const float* __restrict__ emb1, const float* __restrict__ emb2,
    const float* __restrict__ bias,
    __hip_bfloat16* __restrict__ deep, float* __restrict__ p) {
  __shared__ int   sidx[4][40];
  __shared__ float sxv[4][40];
  const int w = threadIdx.x >> 6;
  const int lane = threadIdx.x & 63;
  const int n = blockIdx.x * 4 + w;
  if (lane < Ff) {
    sidx[w][lane] = xi[n * Ff + lane];
    sxv[w][lane]  = xv[n * Ff + lane];
  }
  __syncthreads();

  float s_e = 0.f, sq_e = 0.f;
  #pragma unroll
  for (int j = lane; j < Dd; j += 64) {
    const int f = j >> 4;
    const long off = ((long)f * (Vv + 1) + sidx[w][f]) * Ee + (j & 15);
    const float v = emb2[off] * sxv[w][f];
    deep[(long)n * Dd + j] = __float2bfloat16(v);
    s_e += v; sq_e += v * v;
  }
  s_e  += __shfl_xor(s_e, 16);  sq_e += __shfl_xor(sq_e, 16);
  s_e  += __shfl_xor(s_e, 32);  sq_e += __shfl_xor(sq_e, 32);

  float val = (lane < Ee) ? 0.5f * (s_e * s_e - sq_e) : 0.f;
  if (lane < Ff)
    val += emb1[(long)lane * (Vv + 1) + sidx[w][lane]] * sxv[w][lane];
  #pragma unroll
  for (int d = 1; d < 64; d <<= 1) val += __shfl_xor(val, d);
  if (lane == 0) p[n] = val + bias[0];
}

// ---------------- bf16 MFMA GEMM: C(16384 x 400) = A(16384 x K) @ Wt^T + bias ----------------
// Wt is PRE-TRANSPOSED: Wt[n][k] (row n = output column n, ld = K).
// Block tile 128M x 80N, BK=32, 4 waves, wave tile 32M x 80N (2x5 mfma tiles).
// Fused epilogue: bf16 store + per-column sum/sumsq atomics.
__global__ __launch_bounds__(256) void gemm_bf16(
    const __hip_bfloat16* __restrict__ A, const __hip_bfloat16* __restrict__ Wt,
    const float* __restrict__ bias, __hip_bfloat16* __restrict__ C,
    float* __restrict__ s, float* __restrict__ ss, int K) {
  // LDS rows padded to 40 shorts (80 B) -> 16B-aligned b128 frags, spread banks
  __shared__ uint4 As4[128 * 5];
  __shared__ uint4 Bs4[80 * 5];
  const int tid = threadIdx.x;
  const int n0 = blockIdx.x * 80;
  const int m0 = blockIdx.y * 128;
  const int w = tid >> 6, lane = tid & 63;
  const int lm = lane & 15, qd = lane >> 4;

  floatx4 acc[2][5];
  #pragma unroll
  for (int i = 0; i < 2; ++i)
    #pragma unroll
    for (int j = 0; j < 5; ++j)
      acc[i][j] = (floatx4){0.f, 0.f, 0.f, 0.f};

  const short* As_s = (const short*)As4;
  const short* Bs_s = (const short*)Bs4;
  const int nk = (K + 31) >> 5;

  for (int ks = 0; ks < nk; ++ks) {
    const int k0 = ks << 5;
    // stage A: 512 16B-chunks (m 0..127, kc 0..3)
    #pragma unroll
    for (int cc = 0; cc < 2; ++cc) {
      const int c = tid + cc * 256;
      const int m = c >> 2, kc = c & 3;
      const int k = k0 + kc * 8;
      uint4 v = make_uint4(0, 0, 0, 0);
      if (k < K) v = *(const uint4*)&A[(size_t)(m0 + m) * K + k];
      As4[m * 5 + kc] = v;
    }
    // stage B: 320 16B-chunks (n 0..79, kc 0..3)
    for (int c = tid; c < 320; c += 256) {
      const int n = c >> 2, kc = c & 3;
      const int k = k0 + kc * 8;
      uint4 v = make_uint4(0, 0, 0, 0);
      if (k < K) v = *(const uint4*)&Wt[(size_t)(n0 + n) * K + k];
      Bs4[n * 5 + kc] = v;
    }
    __syncthreads();
    const short8 a0 = *(const short8*)&As_s[(w * 32 + 0  + lm) * 40 + qd * 8];
    const short8 a1 = *(const short8*)&As_s[(w * 32 + 16 + lm) * 40 + qd * 8];
    #pragma unroll
    for (int nt = 0; nt < 5; ++nt) {
      const short8 b = *(const short8*)&Bs_s[(nt * 16 + lm) * 40 + qd * 8];
      acc[0][nt] = __builtin_amdgcn_mfma_f32_16x16x32_bf16(a0, b, acc[0][nt], 0, 0, 0);
      acc[1][nt] = __builtin_amdgcn_mfma_f32_16x16x32_bf16(a1, b, acc[1][nt], 0, 0, 0);
    }
    __syncthreads();
  }

  // epilogue: C/D layout col=lane&15, row=qd*4+reg
  const int rb = m0 + w * 32 + qd * 4;
  #pragma unroll
  for (int nt = 0; nt < 5; ++nt) {
    const int col = n0 + nt * 16 + lm;
    const float bc = bias[col];
    float cs = 0.f, cq = 0.f;
    #pragma unroll
    for (int mt = 0; mt < 2; ++mt) {
      #pragma unroll
      for (int r = 0; r < 4; ++r) {
        const float v = acc[mt][nt][r] + bc;
        const __hip_bfloat16 hv = __float2bfloat16(v);
        C[(size_t)(rb + mt * 16 + r) * Hh + col] = hv;
        const float vf = __bfloat162float(hv);
        cs += vf; cq += vf * vf;
      }
    }
    cs += __shfl_xor(cs, 16); cq += __shfl_xor(cq, 16);
    cs += __shfl_xor(cs, 32); cq += __shfl_xor(cq, 32);
    if (lane < 16) { atomicAdd(&s[col], cs); atomicAdd(&ss[col], cq); }
  }
}

// ---------------- W1 fp32 -> bf16, transposed to [n][k] ----------------
__global__ __launch_bounds__(256) void conv1_kernel(
    const float* __restrict__ W1, __hip_bfloat16* __restrict__ W1t) {
  const int n = blockIdx.x, t = threadIdx.x;
  for (int k = t; k < Dd; k += 256)
    W1t[(size_t)n * Dd + k] = __float2bfloat16(W1[(size_t)k * Hh + n]);
}

// ---------------- BN1 affine coefficients ----------------
__global__ void a1c1_kernel(
    const float* __restrict__ s1, const float* __restrict__ ss1,
    const float* __restrict__ g1, const float* __restrict__ be1,
    float* __restrict__ a1, float* __restrict__ c1) {
  const int t = threadIdx.x;
  if (t < Hh) {
    const float mu = s1[t] * (1.f / Nn);
    const float var = ss1[t] * (1.f / Nn) - mu * mu;
    const float a = g1[t] * rsqrtf(var + EPSf);
    a1[t] = a;
    c1[t] = be1[t] - a * mu;
  }
}

// ---------------- fold BN1 into W2: W2t[n][k] = a1[k]*W2[k][n] (bf16); b2p[n] = b2[n] + sum_k c1[k]*W2[k][n] ----------------
__global__ __launch_bounds__(256) void prep2_kernel(
    const float* __restrict__ W2, const float* __restrict__ a1, const float* __restrict__ c1,
    const float* __restrict__ b2, __hip_bfloat16* __restrict__ W2t, float* __restrict__ b2p) {
  __shared__ float red[256];
  const int n = blockIdx.x, t = threadIdx.x;
  float acc = 0.f;
  for (int k = t; k < Hh; k += 256) {
    const float wv = W2[(size_t)k * Hh + n];
    W2t[(size_t)n * Hh + k] = __float2bfloat16(a1[k] * wv);
    acc += c1[k] * wv;
  }
  red[t] = acc; __syncthreads();
  for (int d = 128; d > 0; d >>= 1) { if (t < d) red[t] += red[t + d]; __syncthreads(); }
  if (t == 0) b2p[n] = b2[n] + red[0];
}

// ---------------- BN2 -> alpha[h], scalar c2 ----------------
__global__ __launch_bounds__(512) void alpha_kernel(
    const float* __restrict__ s2, const float* __restrict__ ss2,
    const float* __restrict__ g2, const float* __restrict__ be2,
    float* __restrict__ alpha, float* __restrict__ c2) {
  __shared__ float red[512];
  const int t = threadIdx.x;
  float part = 0.f;
  if (t < Hh) {
    const float mu = s2[t] * (1.f / Nn);
    const float var = ss2[t] * (1.f / Nn) - mu * mu;
    const float al = g2[t] * rsqrtf(var + EPSf);
    alpha[t] = al;
    part = be2[t] - al * mu;
  }
  red[t] = part;
  __syncthreads();
  for (int d = 256; d > 0; d >>= 1) { if (t < d) red[t] += red[t + d]; __syncthreads(); }
  if (t == 0) c2[0] = red[0];
}

// ---------------- out[n] = p[n] + dot(alpha, x2[n,:]) + c2 ----------------
__global__ __launch_bounds__(256) void final_kernel(
    const __hip_bfloat16* __restrict__ x2, const float* __restrict__ alpha,
    const float* __restrict__ p, const float* __restrict__ c2,
    float* __restrict__ out) {
  const int w = threadIdx.x >> 6, lane = threadIdx.x & 63;
  const int n = blockIdx.x * 4 + w;
  const unsigned short* row = (const unsigned short*)(x2 + (size_t)n * Hh);
  float acc = 0.f;
  for (int h0 = lane * 4; h0 < Hh; h0 += 256) {
    const ushort4 u = *(const ushort4*)&row[h0];
    const float4 al = *(const float4*)&alpha[h0];
    acc += bf2f(u.x) * al.x + bf2f(u.y) * al.y + bf2f(u.z) * al.z + bf2f(u.w) * al.w;
  }
  #pragma unroll
  for (int d = 1; d < 64; d <<= 1) acc += __shfl_xor(acc, d);
  if (lane == 0) out[n] = p[n] + acc + c2[0];
}

extern "C" void kernel_launch(void* const* d_in, const int* in_sizes, int n_in,
                              void* d_out, int out_size, void* d_ws, size_t ws_size,
                              hipStream_t stream) {
  const int*   xi   = (const int*)d_in[0];
  const float* xv   = (const float*)d_in[1];
  const float* emb1 = (const float*)d_in[2];
  const float* emb2 = (const float*)d_in[3];
  const float* W1   = (const float*)d_in[4];
  const float* b1   = (const float*)d_in[5];
  const float* g1   = (const float*)d_in[6];
  const float* be1  = (const float*)d_in[7];
  const float* W2   = (const float*)d_in[8];
  const float* b2   = (const float*)d_in[9];
  const float* g2   = (const float*)d_in[10];
  const float* be2  = (const float*)d_in[11];
  const float* bias = (const float*)d_in[12];
  float* out = (float*)d_out;

  char* ws = (char*)d_ws;
  __hip_bfloat16* deep = (__hip_bfloat16*)ws;                  ws += (size_t)Nn * Dd * 2;   // 20.4 MB
  __hip_bfloat16* x1b  = (__hip_bfloat16*)ws;                  ws += (size_t)Nn * Hh * 2;   // 13.1 MB
  __hip_bfloat16* x2b  = (__hip_bfloat16*)ws;                  ws += (size_t)Nn * Hh * 2;   // 13.1 MB
  __hip_bfloat16* W1t  = (__hip_bfloat16*)ws;                  ws += (size_t)Hh * Dd * 2;   // 499 KB
  __hip_bfloat16* W2t  = (__hip_bfloat16*)ws;                  ws += (size_t)Hh * Hh * 2;   // 320 KB
  float* p    = (float*)ws;  ws += (size_t)Nn * 4;
  float* s1   = (float*)ws;  ws += Hh * 4;
  float* ss1  = (float*)ws;  ws += Hh * 4;
  float* s2   = (float*)ws;  ws += Hh * 4;
  float* ss2  = (float*)ws;  ws += Hh * 4;
  float* a1   = (float*)ws;  ws += Hh * 4;
  float* c1   = (float*)ws;  ws += Hh * 4;
  float* alpha= (float*)ws;  ws += Hh * 4;
  float* b2p  = (float*)ws;  ws += Hh * 4;
  float* c2   = (float*)ws;  ws += 16;

  // zero the atomic stat accumulators (s1,ss1,s2,ss2 contiguous)
  hipMemsetAsync(s1, 0, 4 * Hh * sizeof(float), stream);

  embed_kernel<<<Nn / 4, 256, 0, stream>>>(xi, xv, emb1, emb2, bias, deep, p);
  conv1_kernel<<<Hh, 256, 0, stream>>>(W1, W1t);

  gemm_bf16<<<dim3(5, Nn / 128), 256, 0, stream>>>(deep, W1t, b1, x1b, s1, ss1, Dd);
  a1c1_kernel<<<1, 512, 0, stream>>>(s1, ss1, g1, be1, a1, c1);
  prep2_kernel<<<Hh, 256, 0, stream>>>(W2, a1, c1, b2, W2t, b2p);

  gemm_bf16<<<dim3(5, Nn / 128), 256, 0, stream>>>(x1b, W2t, b2p, x2b, s2, ss2, Hh);
  alpha_kernel<<<1, 512, 0, stream>>>(s2, ss2, g2, be2, alpha, c2);

  final_kernel<<<Nn / 4, 256, 0, stream>>>(x2b, alpha, p, c2, out);
}

// Round 3
// 432.478 us; speedup vs baseline: 1.5277x; 1.0180x over previous
//
#include <hip/hip_runtime.h>
#include <hip/hip_bf16.h>

#define Nn 16384
#define Ff 39
#define Vv 100000
#define Ee 16
#define Dd 624      // F*E
#define Hh 400
#define EPSf 1e-5f

typedef short short8 __attribute__((ext_vector_type(8)));
typedef float floatx4 __attribute__((ext_vector_type(4)));

__device__ __forceinline__ float bf2f(unsigned short v) {
  union { unsigned int u; float f; } x; x.u = ((unsigned int)v) << 16; return x.f;
}

// ---------------- Kernel 1: embedding gather + FM  |  W1 transpose->bf16  |  zero stats ----------------
// blocks [0,4096): embed rows (1 wave/row, 4 rows/block)
// blocks [4096,4496): W1t[n][k] = bf16(W1[k][n])
// block 4496: zero the 4*400 stat accumulators
__global__ __launch_bounds__(256) void embed_kernel(
    const int* __restrict__ xi, const float* __restrict__ xv,
    const float* __restrict__ emb1, const float* __restrict__ emb2,
    const float* __restrict__ bias, const float* __restrict__ W1,
    __hip_bfloat16* __restrict__ deep, float* __restrict__ p,
    __hip_bfloat16* __restrict__ W1t, float* __restrict__ stats) {
  const int b = blockIdx.x;
  if (b >= 4096) {
    if (b == 4496) {
      for (int i = threadIdx.x; i < 1600; i += 256) stats[i] = 0.f;
    } else {
      const int n = b - 4096;
      for (int k = threadIdx.x; k < Dd; k += 256)
        W1t[(size_t)n * Dd + k] = __float2bfloat16(W1[(size_t)k * Hh + n]);
    }
    return;
  }
  __shared__ int   sidx[4][40];
  __shared__ float sxv[4][40];
  const int w = threadIdx.x >> 6;
  const int lane = threadIdx.x & 63;
  const int n = b * 4 + w;
  if (lane < Ff) {
    sidx[w][lane] = xi[n * Ff + lane];
    sxv[w][lane]  = xv[n * Ff + lane];
  }
  __syncthreads();

  float s_e = 0.f, sq_e = 0.f;
  #pragma unroll
  for (int j = lane; j < Dd; j += 64) {
    const int f = j >> 4;
    const long off = ((long)f * (Vv + 1) + sidx[w][f]) * Ee + (j & 15);
    const float v = emb2[off] * sxv[w][f];
    deep[(long)n * Dd + j] = __float2bfloat16(v);
    s_e += v; sq_e += v * v;
  }
  s_e  += __shfl_xor(s_e, 16);  sq_e += __shfl_xor(sq_e, 16);
  s_e  += __shfl_xor(s_e, 32);  sq_e += __shfl_xor(sq_e, 32);

  float val = (lane < Ee) ? 0.5f * (s_e * s_e - sq_e) : 0.f;
  if (lane < Ff)
    val += emb1[(long)lane * (Vv + 1) + sidx[w][lane]] * sxv[w][lane];
  #pragma unroll
  for (int d = 1; d < 64; d <<= 1) val += __shfl_xor(val, d);
  if (lane == 0) p[n] = val + bias[0];
}

// ---------------- bf16 MFMA GEMM: C(16384 x 400) = A(16384 x K) @ Wt^T + bias ----------------
// Wt PRE-TRANSPOSED [n][k]. Block tile 128M x 80N, BK=64, 4 waves, wave tile 32M x 80N.
// LDS rows padded to 72 shorts (144 B): 36-bank stride -> only 2-way conflicts (free).
// Fused epilogue: bf16 store + per-column sum/sumsq atomics.
__global__ __launch_bounds__(256) void gemm_bf16(
    const __hip_bfloat16* __restrict__ A, const __hip_bfloat16* __restrict__ Wt,
    const float* __restrict__ bias, __hip_bfloat16* __restrict__ C,
    float* __restrict__ s, float* __restrict__ ss, int K) {
  __shared__ uint4 As4[128 * 9];
  __shared__ uint4 Bs4[80 * 9];
  const int tid = threadIdx.x;
  const int n0 = blockIdx.x * 80;
  const int m0 = blockIdx.y * 128;
  const int w = tid >> 6, lane = tid & 63;
  const int lm = lane & 15, qd = lane >> 4;

  floatx4 acc[2][5];
  #pragma unroll
  for (int i = 0; i < 2; ++i)
    #pragma unroll
    for (int j = 0; j < 5; ++j)
      acc[i][j] = (floatx4){0.f, 0.f, 0.f, 0.f};

  const short* As_s = (const short*)As4;
  const short* Bs_s = (const short*)Bs4;
  const int nk = (K + 63) >> 6;

  for (int ks = 0; ks < nk; ++ks) {
    const int k0 = ks << 6;
    // stage A: 1024 16B-chunks (m 0..127, kc 0..7)
    #pragma unroll
    for (int cc = 0; cc < 4; ++cc) {
      const int c = tid + cc * 256;
      const int m = c >> 3, kc = c & 7;
      const int k = k0 + kc * 8;
      uint4 v = make_uint4(0, 0, 0, 0);
      if (k < K) v = *(const uint4*)&A[(size_t)(m0 + m) * K + k];
      As4[m * 9 + kc] = v;
    }
    // stage B: 640 16B-chunks (n 0..79, kc 0..7)
    for (int c = tid; c < 640; c += 256) {
      const int n = c >> 3, kc = c & 7;
      const int k = k0 + kc * 8;
      uint4 v = make_uint4(0, 0, 0, 0);
      if (k < K) v = *(const uint4*)&Wt[(size_t)(n0 + n) * K + k];
      Bs4[n * 9 + kc] = v;
    }
    __syncthreads();
    #pragma unroll
    for (int h = 0; h < 2; ++h) {
      const int ko = h * 32 + qd * 8;
      const short8 a0 = *(const short8*)&As_s[(w * 32 + 0  + lm) * 72 + ko];
      const short8 a1 = *(const short8*)&As_s[(w * 32 + 16 + lm) * 72 + ko];
      #pragma unroll
      for (int nt = 0; nt < 5; ++nt) {
        const short8 b = *(const short8*)&Bs_s[(nt * 16 + lm) * 72 + ko];
        acc[0][nt] = __builtin_amdgcn_mfma_f32_16x16x32_bf16(a0, b, acc[0][nt], 0, 0, 0);
        acc[1][nt] = __builtin_amdgcn_mfma_f32_16x16x32_bf16(a1, b, acc[1][nt], 0, 0, 0);
      }
    }
    __syncthreads();
  }

  // epilogue: C/D layout col=lane&15, row=qd*4+reg
  const int rb = m0 + w * 32 + qd * 4;
  #pragma unroll
  for (int nt = 0; nt < 5; ++nt) {
    const int col = n0 + nt * 16 + lm;
    const float bc = bias[col];
    float cs = 0.f, cq = 0.f;
    #pragma unroll
    for (int mt = 0; mt < 2; ++mt) {
      #pragma unroll
      for (int r = 0; r < 4; ++r) {
        const float v = acc[mt][nt][r] + bc;
        const __hip_bfloat16 hv = __float2bfloat16(v);
        C[(size_t)(rb + mt * 16 + r) * Hh + col] = hv;
        const float vf = __bfloat162float(hv);
        cs += vf; cq += vf * vf;
      }
    }
    cs += __shfl_xor(cs, 16); cq += __shfl_xor(cq, 16);
    cs += __shfl_xor(cs, 32); cq += __shfl_xor(cq, 32);
    if (lane < 16) { atomicAdd(&s[col], cs); atomicAdd(&ss[col], cq); }
  }
}

// ---------------- prep2 (BN1 coefficients inline): W2t[n][k] = a1[k]*W2[k][n]; b2p[n] = b2[n] + sum_k c1[k]*W2[k][n] ----------------
__global__ __launch_bounds__(256) void prep2_kernel(
    const float* __restrict__ W2,
    const float* __restrict__ s1, const float* __restrict__ ss1,
    const float* __restrict__ g1, const float* __restrict__ be1,
    const float* __restrict__ b2, __hip_bfloat16* __restrict__ W2t, float* __restrict__ b2p) {
  __shared__ float sa1[Hh], sc1[Hh];
  __shared__ float red[256];
  const int n = blockIdx.x, t = threadIdx.x;
  for (int k = t; k < Hh; k += 256) {
    const float mu = s1[k] * (1.f / Nn);
    const float var = ss1[k] * (1.f / Nn) - mu * mu;
    const float a = g1[k] * rsqrtf(var + EPSf);
    sa1[k] = a;
    sc1[k] = be1[k] - a * mu;
  }
  __syncthreads();
  float acc = 0.f;
  for (int k = t; k < Hh; k += 256) {
    const float wv = W2[(size_t)k * Hh + n];
    W2t[(size_t)n * Hh + k] = __float2bfloat16(sa1[k] * wv);
    acc += sc1[k] * wv;
  }
  red[t] = acc; __syncthreads();
  for (int d = 128; d > 0; d >>= 1) { if (t < d) red[t] += red[t + d]; __syncthreads(); }
  if (t == 0) b2p[n] = b2[n] + red[0];
}

// ---------------- final (BN2 alpha/c2 inline): out[n] = p[n] + dot(alpha, x2[n,:]) + c2 ----------------
__global__ __launch_bounds__(256) void final_kernel(
    const __hip_bfloat16* __restrict__ x2,
    const float* __restrict__ s2, const float* __restrict__ ss2,
    const float* __restrict__ g2, const float* __restrict__ be2,
    const float* __restrict__ p, float* __restrict__ out) {
  __shared__ float sal[Hh];
  __shared__ float red[256];
  const int t = threadIdx.x;
  float part = 0.f;
  for (int h = t; h < Hh; h += 256) {
    const float mu = s2[h] * (1.f / Nn);
    const float var = ss2[h] * (1.f / Nn) - mu * mu;
    const float al = g2[h] * rsqrtf(var + EPSf);
    sal[h] = al;
    part += be2[h] - al * mu;
  }
  red[t] = part; __syncthreads();
  for (int d = 128; d > 0; d >>= 1) { if (t < d) red[t] += red[t + d]; __syncthreads(); }
  __syncthreads();
  const float c2 = red[0];

  const int w = t >> 6, lane = t & 63;
  const int n = blockIdx.x * 4 + w;
  const unsigned short* row = (const unsigned short*)(x2 + (size_t)n * Hh);
  float acc = 0.f;
  for (int h0 = lane * 4; h0 < Hh; h0 += 256) {
    const ushort4 u = *(const ushort4*)&row[h0];
    acc += bf2f(u.x) * sal[h0] + bf2f(u.y) * sal[h0 + 1]
         + bf2f(u.z) * sal[h0 + 2] + bf2f(u.w) * sal[h0 + 3];
  }
  #pragma unroll
  for (int d = 1; d < 64; d <<= 1) acc += __shfl_xor(acc, d);
  if (lane == 0) out[n] = p[n] + acc + c2;
}

extern "C" void kernel_launch(void* const* d_in, const int* in_sizes, int n_in,
                              void* d_out, int out_size, void* d_ws, size_t ws_size,
                              hipStream_t stream) {
  const int*   xi   = (const int*)d_in[0];
  const float* xv   = (const float*)d_in[1];
  const float* emb1 = (const float*)d_in[2];
  const float* emb2 = (const float*)d_in[3];
  const float* W1   = (const float*)d_in[4];
  const float* b1   = (const float*)d_in[5];
  const float* g1   = (const float*)d_in[6];
  const float* be1  = (const float*)d_in[7];
  const float* W2   = (const float*)d_in[8];
  const float* b2   = (const float*)d_in[9];
  const float* g2   = (const float*)d_in[10];
  const float* be2  = (const float*)d_in[11];
  const float* bias = (const float*)d_in[12];
  float* out = (float*)d_out;

  char* ws = (char*)d_ws;
  __hip_bfloat16* deep = (__hip_bfloat16*)ws;  ws += (size_t)Nn * Dd * 2;
  __hip_bfloat16* x1b  = (__hip_bfloat16*)ws;  ws += (size_t)Nn * Hh * 2;
  __hip_bfloat16* x2b  = (__hip_bfloat16*)ws;  ws += (size_t)Nn * Hh * 2;
  __hip_bfloat16* W1t  = (__hip_bfloat16*)ws;  ws += (size_t)Hh * Dd * 2;
  __hip_bfloat16* W2t  = (__hip_bfloat16*)ws;  ws += (size_t)Hh * Hh * 2;
  float* p    = (float*)ws;  ws += (size_t)Nn * 4;
  float* s1   = (float*)ws;  ws += Hh * 4;   // s1,ss1,s2,ss2 contiguous (zeroed by embed launch)
  float* ss1  = (float*)ws;  ws += Hh * 4;
  float* s2   = (float*)ws;  ws += Hh * 4;
  float* ss2  = (float*)ws;  ws += Hh * 4;
  float* b2p  = (float*)ws;  ws += Hh * 4;

  embed_kernel<<<4497, 256, 0, stream>>>(xi, xv, emb1, emb2, bias, W1, deep, p, W1t, s1);
  gemm_bf16<<<dim3(5, Nn / 128), 256, 0, stream>>>(deep, W1t, b1, x1b, s1, ss1, Dd);
  prep2_kernel<<<Hh, 256, 0, stream>>>(W2, s1, ss1, g1, be1, b2, W2t, b2p);
  gemm_bf16<<<dim3(5, Nn / 128), 256, 0, stream>>>(x1b, W2t, b2p, x2b, s2, ss2, Hh);
  final_kernel<<<Nn / 4, 256, 0, stream>>>(x2b, s2, ss2, g2, be2, p, out);
}